// Round 19
// baseline (239.762 us; speedup 1.0000x reference)
//
#include <hip/hip_runtime.h>

#define TT 8
#define VV 10000
#define EE 160000
#define HH 64
#define NN 16
#define CO 64
#define NOUT 224  // 160 conv outs + 64 residual
#define RR (TT * VV)
#define PP 32            // partitions per timestep
#define CHUNK (EE / PP)  // 5000 edges per partition

typedef float f32x4 __attribute__((ext_vector_type(4)));
typedef float f32x2 __attribute__((ext_vector_type(2)));
typedef __bf16 bf16x8 __attribute__((ext_vector_type(8)));
typedef unsigned int uint;

#define GLOBAL_AS __attribute__((address_space(1)))
#define LDS_AS __attribute__((address_space(3)))

__device__ __forceinline__ unsigned short f2bf(float f) {
  union { float f; unsigned u; } v;
  v.f = f;
  unsigned r = v.u + 0x7fffu + ((v.u >> 16) & 1u);
  return (unsigned short)(r >> 16);
}
__device__ __forceinline__ float bf2f(unsigned h) {
  union { unsigned u; float f; } v;
  v.u = h << 16;
  return v.f;
}
// unpack packed bf16 pair (lo,hi) of one uint into f32x2
__device__ __forceinline__ f32x2 unpk(uint u) {
  union { uint u; float f; } lo, hi;
  lo.u = u << 16;
  hi.u = u & 0xffff0000u;
  f32x2 r;
  r.x = lo.f;
  r.y = hi.f;
  return r;
}
__device__ __forceinline__ uint pk2(f32x2 v) { return (uint)f2bf(v.x) | ((uint)f2bf(v.y) << 16); }
__device__ __forceinline__ f32x2 red2_1632(f32x2 v) {
  v.x += __shfl_xor(v.x, 16, 64);
  v.y += __shfl_xor(v.y, 16, 64);
  v.x += __shfl_xor(v.x, 32, 64);
  v.y += __shfl_xor(v.y, 32, 64);
  return v;
}

// ==== CSR build, hierarchical, no global atomics, saturated grids ====
__global__ __launch_bounds__(1024) void hist_part(const int* __restrict__ ei, int* __restrict__ part) {
  __shared__ int cnt[VV];
  const int t = blockIdx.x / PP, p = blockIdx.x % PP;
  const int tid = threadIdx.x;
  for (int i = tid; i < VV; i += 1024) cnt[i] = 0;
  __syncthreads();
  const int* dstp = ei + (long)(t * 2 + 1) * EE + p * CHUNK;
  for (int e = tid; e < CHUNK; e += 1024) atomicAdd(&cnt[dstp[e]], 1);
  __syncthreads();
  int* op = part + (long)blockIdx.x * VV;
  for (int i = tid; i < VV; i += 1024) op[i] = cnt[i];
}

__global__ __launch_bounds__(256) void part_prefix(int* __restrict__ part, int* __restrict__ cnt) {
  int idx = blockIdx.x * 256 + threadIdx.x;  // t*VV + v
  if (idx >= RR) return;
  int t = idx / VV, v = idx - t * VV;
  long base = ((long)t * PP) * VV + v;
  int x[PP];
#pragma unroll
  for (int p = 0; p < PP; p++) x[p] = part[base + (long)p * VV];
  int s = 0;
#pragma unroll
  for (int p = 0; p < PP; p++) {
    int xx = x[p];
    part[base + (long)p * VV] = s;
    s += xx;
  }
  cnt[idx] = s;
}

__global__ __launch_bounds__(256) void scan_block(const int* __restrict__ cnt, int* __restrict__ off,
                                                  int* __restrict__ bsum) {
  __shared__ int sm[256];
  int i = blockIdx.x * 256 + threadIdx.x;
  int v = (i < RR) ? cnt[i] : 0;
  sm[threadIdx.x] = v;
  __syncthreads();
  for (int d = 1; d < 256; d <<= 1) {
    int t = (threadIdx.x >= d) ? sm[threadIdx.x - d] : 0;
    __syncthreads();
    sm[threadIdx.x] += t;
    __syncthreads();
  }
  if (i < RR) off[i] = sm[threadIdx.x] - v;
  if (threadIdx.x == 255) bsum[blockIdx.x] = sm[255];
}

__global__ __launch_bounds__(512) void scan_tops(int* __restrict__ bsum, int nb) {
  __shared__ int sm[512];
  int v = (threadIdx.x < nb) ? bsum[threadIdx.x] : 0;
  sm[threadIdx.x] = v;
  __syncthreads();
  for (int d = 1; d < 512; d <<= 1) {
    int t = (threadIdx.x >= d) ? sm[threadIdx.x - d] : 0;
    __syncthreads();
    sm[threadIdx.x] += t;
    __syncthreads();
  }
  if (threadIdx.x < nb) bsum[threadIdx.x] = sm[threadIdx.x] - v;
}

__global__ __launch_bounds__(256) void scan_add(int* __restrict__ off, const int* __restrict__ bsum) {
  int i = blockIdx.x * 256 + threadIdx.x;
  if (i < RR) off[i] += bsum[blockIdx.x];
  if (i == 0) off[RR] = TT * EE;
}

__global__ __launch_bounds__(1024) void scatter_part(const int* __restrict__ ei, const int* __restrict__ off,
                                                     const int* __restrict__ part, int* __restrict__ csr) {
  __shared__ int base_s[VV];
  __shared__ int cnt[VV];
  const int t = blockIdx.x / PP, p = blockIdx.x % PP;
  const int tid = threadIdx.x;
  const int* pp = part + (long)blockIdx.x * VV;
  const int* offt = off + t * VV;
  for (int i = tid; i < VV; i += 1024) {
    base_s[i] = offt[i] + pp[i];
    cnt[i] = 0;
  }
  __syncthreads();
  const int* srcp = ei + (long)(t * 2) * EE + p * CHUNK;
  const int* dstp = ei + (long)(t * 2 + 1) * EE + p * CHUNK;
  for (int e = tid; e < CHUNK; e += 1024) {
    int d = dstp[e];
    int r = atomicAdd(&cnt[d], 1);
    csr[base_s[d] + r] = t * VV + srcp[e];
  }
}

// ---- cast xs -> A_hi[:,0:128] (bf16 hi), A_lo[:,0:128] (bf16 lo) ----
__global__ __launch_bounds__(256) void cast_x0(const float* __restrict__ xs, unsigned short* __restrict__ Ahi,
                                               unsigned short* __restrict__ Alo) {
  int idx = blockIdx.x * 256 + threadIdx.x;  // one per float4, RR*32 total
  int row = idx >> 5, c4 = (idx & 31) * 4;
  float4 v = *reinterpret_cast<const float4*>(&xs[(long)row * 128 + c4]);
  ushort4 hs, ls;
  hs.x = f2bf(v.x); hs.y = f2bf(v.y); hs.z = f2bf(v.z); hs.w = f2bf(v.w);
  ls.x = f2bf(v.x - bf2f(hs.x)); ls.y = f2bf(v.y - bf2f(hs.y));
  ls.z = f2bf(v.z - bf2f(hs.z)); ls.w = f2bf(v.w - bf2f(hs.w));
  *reinterpret_cast<ushort4*>(&Ahi[(long)row * 256 + c4]) = hs;
  *reinterpret_cast<ushort4*>(&Alo[(long)row * 128 + c4]) = ls;
}

// ---- build stacked bf16 weight matrix Bp[n][k] (transposed, row stride Ktot) + bias ----
__global__ __launch_bounds__(256) void prep_b(const float* __restrict__ Wl, const float* __restrict__ Wr,
                                              const float* __restrict__ Wres, const float* __restrict__ bc,
                                              const float* __restrict__ bres, int Cin, int Ktot,
                                              unsigned short* __restrict__ Bp, float* __restrict__ bias) {
  int idx = blockIdx.x * 256 + threadIdx.x;
  if (idx >= NOUT * Ktot) return;
  int n = idx / Ktot, k = idx - n * Ktot;
  int reg = k / Cin, kk = k - reg * Cin;
  float w;
  if (reg == 1)
    w = (n < 160) ? Wr[kk * 160 + n] : 0.f;
  else
    w = (n < 160) ? Wl[kk * 160 + n] : Wres[kk * 64 + (n - 160)];
  Bp[idx] = f2bf(w);
  if (k == 0) bias[n] = (n < 160) ? bc[n] : bres[n - 160];
}

// ---- gather layer 0: 16-lane edge-groups, uint4 loads, XCD-swizzled blocks ----
__global__ __launch_bounds__(256) void gather0(const int* __restrict__ off, const int* __restrict__ csr,
                                               const uint4* __restrict__ X4, uint4* __restrict__ M4) {
  int sb = (blockIdx.x & 7) * 2500 + (blockIdx.x >> 3);  // bijective: 20000 = 8*2500
  int wv = __builtin_amdgcn_readfirstlane(threadIdx.x) >> 6;
  int lane = threadIdx.x & 63;
  int row = sb * 4 + wv;
  int s = off[row], e = off[row + 1];
  int sub = lane >> 4, c = lane & 15;
  f32x2 a0 = {0.f, 0.f}, a1 = a0, a2 = a0, a3 = a0;
  int i = s;
  for (; i + 4 <= e; i += 4) {
    int g = csr[i + sub];
    uint4 w = X4[(long)g * 32 + c];
    a0 += unpk(w.x);
    a1 += unpk(w.y);
    a2 += unpk(w.z);
    a3 += unpk(w.w);
  }
  if (i + sub < e) {
    int g = csr[i + sub];
    uint4 w = X4[(long)g * 32 + c];
    a0 += unpk(w.x);
    a1 += unpk(w.y);
    a2 += unpk(w.z);
    a3 += unpk(w.w);
  }
  a0 = red2_1632(a0);
  a1 = red2_1632(a1);
  a2 = red2_1632(a2);
  a3 = red2_1632(a3);
  if (sub == 0) {
    float inv = 1.f / (float)max(e - s, 1);
    uint4 o;
    o.x = pk2(a0 * inv);
    o.y = pk2(a1 * inv);
    o.z = pk2(a2 * inv);
    o.w = pk2(a3 * inv);
    M4[(long)row * 32 + 16 + c] = o;
  }
}

// ---- gather layer 1: 16-lane edge-groups, uint2 loads, XCD-swizzled blocks ----
__global__ __launch_bounds__(256) void gather1(const int* __restrict__ off, const int* __restrict__ csr,
                                               const uint2* __restrict__ X2, uint2* __restrict__ M2) {
  int sb = (blockIdx.x & 7) * 2500 + (blockIdx.x >> 3);
  int wv = __builtin_amdgcn_readfirstlane(threadIdx.x) >> 6;
  int lane = threadIdx.x & 63;
  int row = sb * 4 + wv;
  int s = off[row], e = off[row + 1];
  int sub = lane >> 4, c = lane & 15;
  f32x2 a0 = {0.f, 0.f}, a1 = a0;
  int i = s;
  for (; i + 4 <= e; i += 4) {
    int g = csr[i + sub];
    uint2 w = X2[(long)g * 64 + c];
    a0 += unpk(w.x);
    a1 += unpk(w.y);
  }
  if (i + sub < e) {
    int g = csr[i + sub];
    uint2 w = X2[(long)g * 64 + c];
    a0 += unpk(w.x);
    a1 += unpk(w.y);
  }
  a0 = red2_1632(a0);
  a1 = red2_1632(a1);
  if (sub == 0) {
    float inv = 1.f / (float)max(e - s, 1);
    uint2 o;
    o.x = pk2(a0 * inv);
    o.y = pk2(a1 * inv);
    M2[(long)row * 64 + 16 + c] = o;
  }
}

// ==== bf16x2 MFMA GEMM, 2-phase double-buffered pipeline (R11-proven config) ====
__device__ __forceinline__ void stage_tile(char* sb, const unsigned short* aptr, long astr,
                                           const unsigned short* Bp, int Ktot, int k0, long row0,
                                           int wid, int lane) {
#pragma unroll
  for (int r = 0; r < 6; ++r) {
    int c = wid * 6 + r;  // 48 chunks of 1024B; 0-15 = A, 16-47 = B (wave-uniform)
    const char* gp;
    if (c < 16) {
      int o = c * 1024 + lane * 16;
      int arow = o >> 7;
      int ac16 = (o >> 4) & 7;
      gp = (const char*)aptr + ((row0 + arow) * astr) * 2 + ((ac16 ^ (arow & 7)) << 4);
    } else {
      int o = (c - 16) * 1024 + lane * 16;
      int brow = o >> 7;
      int bc16 = (o >> 4) & 7;
      int browc = brow < NOUT ? brow : (NOUT - 1);
      gp = (const char*)Bp + ((long)browc * Ktot + k0) * 2 + ((bc16 ^ (brow & 7)) << 4);
    }
    __builtin_amdgcn_global_load_lds((const GLOBAL_AS uint*)gp, (LDS_AS uint*)(sb + c * 1024), 16, 0, 0);
  }
}

__global__ __launch_bounds__(512) void gemm_kernel(const unsigned short* __restrict__ Ahi,
                                                   const unsigned short* __restrict__ Alo,
                                                   const unsigned short* __restrict__ Bp,
                                                   const float* __restrict__ bias, float* __restrict__ outs,
                                                   int Ktot, int sw1, int lda, int ldalo) {
  __shared__ char sbuf[2][49152];
  const int tid = threadIdx.x;
  const long row0 = (long)blockIdx.x * 128;
  const int wid = tid >> 6, lane = tid & 63;
  const int wr = wid >> 1, wc = wid & 1;  // wave = 32 rows x 112 cols
  const int l15 = lane & 15, lg = lane >> 4;
  f32x4 acc[2][7];
#pragma unroll
  for (int i = 0; i < 2; i++)
#pragma unroll
    for (int n = 0; n < 7; n++) acc[i][n] = (f32x4)(0.f);

  const int nt = Ktot / 64;
  auto asel = [&](int k0, const unsigned short*& aptr, long& astr) {
    if (k0 < sw1) { aptr = Ahi + k0; astr = lda; }
    else { aptr = Alo + (k0 - sw1); astr = ldalo; }
  };
  {
    const unsigned short* aptr; long astr;
    asel(0, aptr, astr);
    stage_tile(sbuf[0], aptr, astr, Bp, Ktot, 0, row0, wid, lane);
  }
  for (int kt = 0; kt < nt; ++kt) {
    const int b = kt & 1;
    if (kt + 1 < nt) {
      const unsigned short* aptr; long astr;
      asel((kt + 1) * 64, aptr, astr);
      stage_tile(sbuf[b ^ 1], aptr, astr, Bp, Ktot, (kt + 1) * 64, row0, wid, lane);
      asm volatile("s_waitcnt vmcnt(6)" ::: "memory");  // current buf's 6 loads landed
    } else {
      asm volatile("s_waitcnt vmcnt(0)" ::: "memory");
    }
    __builtin_amdgcn_s_barrier();
    __builtin_amdgcn_sched_barrier(0);
    const char* sb = sbuf[b];
#pragma unroll
    for (int kk = 0; kk < 2; ++kk) {
      const int cswz = (((kk << 2) | lg) ^ (l15 & 7)) << 4;
      bf16x8 af0 = *reinterpret_cast<const bf16x8*>(sb + (wr * 32 + l15) * 128 + cswz);
      bf16x8 af1 = *reinterpret_cast<const bf16x8*>(sb + (wr * 32 + 16 + l15) * 128 + cswz);
#pragma unroll
      for (int n = 0; n < 7; ++n) {
        bf16x8 bfr = *reinterpret_cast<const bf16x8*>(sb + 16384 + (wc * 112 + n * 16 + l15) * 128 + cswz);
        acc[0][n] = __builtin_amdgcn_mfma_f32_16x16x32_bf16(af0, bfr, acc[0][n], 0, 0, 0);
        acc[1][n] = __builtin_amdgcn_mfma_f32_16x16x32_bf16(af1, bfr, acc[1][n], 0, 0, 0);
      }
    }
    __builtin_amdgcn_sched_barrier(0);
    __builtin_amdgcn_s_barrier();  // all waves done reading buf b (next iter overwrites it)
  }
#pragma unroll
  for (int i = 0; i < 2; i++) {
    long grow = row0 + wr * 32 + i * 16 + lg * 4;
#pragma unroll
    for (int n = 0; n < 7; n++) {
      int gcol = wc * 112 + n * 16 + l15;
      float bv = bias[gcol];
#pragma unroll
      for (int r = 0; r < 4; r++) outs[(grow + r) * NOUT + gcol] = acc[i][n][r] + bv;
    }
  }
}

// ---- diagonal SSM scan over T, next-t bundle prefetch, f32x2 packed math ----
// __launch_bounds__(256,4): 128-VGPR budget so BOTH bundles stay register-resident
// (R18 post-mortem: at 36 VGPR the compiler re-materialized the prefetch loads).
// MODE 0: tkmix + write bf16 hi/lo all T. MODE 1: last-T only + fused final matmul.
template <int MODE>
__global__ __launch_bounds__(256, 4) void ssm_kernel(const float* __restrict__ outs, const float* __restrict__ logA,
                                                     const float* __restrict__ dlt, const float* __restrict__ tkw,
                                                     const float* __restrict__ tkb, unsigned short* __restrict__ xhi,
                                                     unsigned short* __restrict__ xlo, const float* __restrict__ Wmlp,
                                                     const float* __restrict__ bmlp, float* __restrict__ out) {
  __shared__ float ylds[4][64];  // MODE 1 only
  int wv = __builtin_amdgcn_readfirstlane(threadIdx.x) >> 6;  // wave-uniform wave id
  int v = blockIdx.x * 4 + wv;
  int h = threadIdx.x & 63;
  f32x2 a2v[8], sv[8];
#pragma unroll
  for (int p = 0; p < 8; p++) {
    a2v[p].x = -__expf(logA[h * NN + 2 * p]) * 1.44269504f;
    a2v[p].y = -__expf(logA[h * NN + 2 * p + 1]) * 1.44269504f;
    sv[p] = (f32x2){0.f, 0.f};
  }
  float dh = dlt[h];
  float w0 = 0.f, w1 = 0.f, w2 = 0.f, tb = 0.f;
  float xhm = 0.f, xh0 = 0.f;
  if (MODE == 0) {
    w0 = tkw[h * 3 + 0];
    w1 = tkw[h * 3 + 1];
    w2 = tkw[h * 3 + 2];
    tb = tkb[h];
  }
  // bundle for row t: dtr(+dh pre-added), xvh, rres, B (and C for MODE 0)
  const float* rp = outs + (long)v * NOUT;
  float dtr_c = rp[HH + h] + dh;
  float xvh_c = rp[h];
  float rres_c = rp[160 + h];
  float4 qb_c[4], qc_c[4];
  {
    const float4* bc4 = reinterpret_cast<const float4*>(rp + 2 * HH);
    qb_c[0] = bc4[0]; qb_c[1] = bc4[1]; qb_c[2] = bc4[2]; qb_c[3] = bc4[3];
    if (MODE == 0) { qc_c[0] = bc4[4]; qc_c[1] = bc4[5]; qc_c[2] = bc4[6]; qc_c[3] = bc4[7]; }
  }
  if (MODE == 0) xh0 = xvh_c;
#pragma unroll
  for (int t = 0; t < TT; t++) {
    // prefetch bundle t+1 (full iteration of latency cover)
    const float* rpn = rp + (long)VV * NOUT;
    float dtr_n = 0.f, xvh_n = 0.f, rres_n = 0.f;
    float4 qb_n[4], qc_n[4];
    if (t + 1 < TT) {
      dtr_n = rpn[HH + h] + dh;
      xvh_n = rpn[h];
      rres_n = rpn[160 + h];
      const float4* bc4n = reinterpret_cast<const float4*>(rpn + 2 * HH);
      qb_n[0] = bc4n[0]; qb_n[1] = bc4n[1]; qb_n[2] = bc4n[2]; qb_n[3] = bc4n[3];
      if (MODE == 0) { qc_n[0] = bc4n[4]; qc_n[1] = bc4n[5]; qc_n[2] = bc4n[6]; qc_n[3] = bc4n[7]; }
    }
    float dtr = dtr_c;
    float dt = dtr > 20.f ? dtr : __logf(1.f + __expf(dtr));
    float xv;
    if (MODE == 0) {
      float xh1 = (t + 1 < TT) ? xvh_n : 0.f;
      xv = fmaf(xhm, w0, fmaf(xh0, w1, fmaf(xh1, w2, tb)));
      xhm = xh0;
      xh0 = xh1;
    } else {
      xv = xvh_c;
    }
    f32x2 bbv[8] = {{qb_c[0].x, qb_c[0].y}, {qb_c[0].z, qb_c[0].w}, {qb_c[1].x, qb_c[1].y}, {qb_c[1].z, qb_c[1].w},
                    {qb_c[2].x, qb_c[2].y}, {qb_c[2].z, qb_c[2].w}, {qb_c[3].x, qb_c[3].y}, {qb_c[3].z, qb_c[3].w}};
    float dtxv = dt * xv;
#pragma unroll
    for (int p = 0; p < 8; p++) {
      f32x2 arg = a2v[p] * dt;
      f32x2 e = {exp2f(arg.x), exp2f(arg.y)};
      sv[p] = e * sv[p] + bbv[p] * dtxv;
    }
    const bool needY = (MODE == 0) || (t == TT - 1);
    if (needY) {
      float4 c0, c1, c2, c3;
      if (MODE == 0) {
        c0 = qc_c[0]; c1 = qc_c[1]; c2 = qc_c[2]; c3 = qc_c[3];
      } else {
        const float4* bc4 = reinterpret_cast<const float4*>(rp + 2 * HH);
        c0 = bc4[4]; c1 = bc4[5]; c2 = bc4[6]; c3 = bc4[7];
      }
      f32x2 ccv[8] = {{c0.x, c0.y}, {c0.z, c0.w}, {c1.x, c1.y}, {c1.z, c1.w},
                      {c2.x, c2.y}, {c2.z, c2.w}, {c3.x, c3.y}, {c3.z, c3.w}};
      f32x2 yv = {0.f, 0.f};
#pragma unroll
      for (int p = 0; p < 8; p++) yv += sv[p] * ccv[p];
      float y = fmaxf(yv.x + yv.y, 0.f);
      float z = y + rres_c;
      float s1 = z, s2 = z * z;
#pragma unroll
      for (int m = 32; m > 0; m >>= 1) {
        s1 += __shfl_xor(s1, m, 64);
        s2 += __shfl_xor(s2, m, 64);
      }
      float mu = s1 * (1.f / 64.f);
      float var = fmaf(s2, 1.f / 64.f, -mu * mu);
      float o = (z - mu) * rsqrtf(var + 1e-5f);
      if (MODE == 0) {
        long row = (long)t * VV + v;
        unsigned short hi = f2bf(o);
        xhi[row * 256 + h] = hi;
        xlo[row * 128 + h] = f2bf(o - bf2f(hi));
      } else {
        ylds[wv][h] = o;
      }
    }
    // rotate bundle (register renaming under full unroll)
    dtr_c = dtr_n;
    xvh_c = xvh_n;
    rres_c = rres_n;
    qb_c[0] = qb_n[0]; qb_c[1] = qb_n[1]; qb_c[2] = qb_n[2]; qb_c[3] = qb_n[3];
    if (MODE == 0) { qc_c[0] = qc_n[0]; qc_c[1] = qc_n[1]; qc_c[2] = qc_n[2]; qc_c[3] = qc_n[3]; }
    rp = rpn;
  }
  if (MODE == 1) {
    __syncthreads();
    float acc = bmlp[h];
#pragma unroll 8
    for (int h2 = 0; h2 < 64; h2++) acc = fmaf(ylds[wv][h2], Wmlp[h2 * CO + h], acc);
    out[(long)v * CO + h] = acc;
  }
}

extern "C" void kernel_launch(void* const* d_in, const int* in_sizes, int n_in, void* d_out, int out_size,
                              void* d_ws, size_t ws_size, hipStream_t stream) {
  const float* xs = (const float*)d_in[0];
  const int* ei = (const int*)d_in[1];
  const float* Wl0 = (const float*)d_in[2];
  const float* Wr0 = (const float*)d_in[3];
  const float* bc0 = (const float*)d_in[4];
  const float* Wl1 = (const float*)d_in[5];
  const float* Wr1 = (const float*)d_in[6];
  const float* bc1 = (const float*)d_in[7];
  const float* Wres0 = (const float*)d_in[8];
  const float* bres0 = (const float*)d_in[9];
  const float* Wres1 = (const float*)d_in[10];
  const float* bres1 = (const float*)d_in[11];
  const float* tkw = (const float*)d_in[12];
  const float* tkb = (const float*)d_in[13];
  const float* logA = (const float*)d_in[14];
  const float* dlt = (const float*)d_in[15];
  const float* Wmlp = (const float*)d_in[16];
  const float* bmlp = (const float*)d_in[17];
  float* out = (float*)d_out;

  float* outs = (float*)d_ws;                          // RR*224 f32
  unsigned short* Ahi = (unsigned short*)(outs + (long)RR * NOUT);  // RR*256 bf16
  unsigned short* Alo = Ahi + (long)RR * 256;          // RR*128 bf16
  unsigned short* Bp0 = Alo + (long)RR * 128;          // 224*384
  unsigned short* Bp1 = Bp0 + 224 * 384;               // 224*192
  float* bias0 = (float*)(Bp1 + 224 * 192);            // 224
  float* bias1 = bias0 + 224;                          // 224
  int* off = (int*)(bias1 + 224);                      // RR+1
  int* csr = off + RR + 1;                             // TT*EE
  int* cnt = csr + TT * EE;                            // RR
  int* bsum = cnt + RR;                                // 512
  // part[256][VV] aliases outs: dead before the first gemm writes outs.
  int* part = (int*)outs;

  const int NB = (RR + 255) / 256;  // 313

  // ---- CSR build: 6 kernels, LDS histograms, no global atomics, saturated ----
  hist_part<<<TT * PP, 1024, 0, stream>>>(ei, part);
  part_prefix<<<NB, 256, 0, stream>>>(part, cnt);
  scan_block<<<NB, 256, 0, stream>>>(cnt, off, bsum);
  scan_tops<<<1, 512, 0, stream>>>(bsum, NB);
  scan_add<<<NB, 256, 0, stream>>>(off, bsum);
  scatter_part<<<TT * PP, 1024, 0, stream>>>(ei, off, part, csr);

  // ---- weight prep (hi-only, bf16x2) ----
  prep_b<<<(NOUT * 384 + 255) / 256, 256, 0, stream>>>(Wl0, Wr0, Wres0, bc0, bres0, 128, 384, Bp0, bias0);
  prep_b<<<(NOUT * 192 + 255) / 256, 256, 0, stream>>>(Wl1, Wr1, Wres1, bc1, bres1, 64, 192, Bp1, bias1);

  // ---- layer 0: K = 256 (x_hi|mean) + 128 (x_lo) ----
  cast_x0<<<RR * 32 / 256, 256, 0, stream>>>(xs, Ahi, Alo);
  gather0<<<RR / 4, 256, 0, stream>>>(off, csr, (const uint4*)Ahi, (uint4*)Ahi);
  gemm_kernel<<<RR / 128, 512, 0, stream>>>(Ahi, Alo, Bp0, bias0, outs, 384, 256, 256, 128);
  ssm_kernel<0><<<VV / 4, 256, 0, stream>>>(outs, logA, dlt, tkw, tkb, Ahi, Alo, nullptr, nullptr, nullptr);

  // ---- layer 1: K = 128 (x_hi|mean) + 64 (x_lo); ssm fuses final matmul ----
  gather1<<<RR / 4, 256, 0, stream>>>(off, csr, (const uint2*)Ahi, (uint2*)Ahi);
  gemm_kernel<<<RR / 128, 512, 0, stream>>>(Ahi, Alo, Bp1, bias1, outs, 192, 128, 256, 128);
  ssm_kernel<1><<<VV / 4, 256, 0, stream>>>(outs, logA + HH * NN, dlt + HH, nullptr, nullptr, nullptr, nullptr,
                                            Wmlp, bmlp, out);
}

// Round 20
// 230.100 us; speedup vs baseline: 1.0420x; 1.0420x over previous
//
#include <hip/hip_runtime.h>

#define TT 8
#define VV 10000
#define EE 160000
#define HH 64
#define NN 16
#define CO 64
#define NOUT 224  // 160 conv outs + 64 residual
#define RR (TT * VV)
#define PP 32            // partitions per timestep
#define CHUNK (EE / PP)  // 5000 edges per partition

typedef float f32x4 __attribute__((ext_vector_type(4)));
typedef float f32x2 __attribute__((ext_vector_type(2)));
typedef __bf16 bf16x8 __attribute__((ext_vector_type(8)));
typedef unsigned int uint;

#define GLOBAL_AS __attribute__((address_space(1)))
#define LDS_AS __attribute__((address_space(3)))

__device__ __forceinline__ unsigned short f2bf(float f) {
  union { float f; unsigned u; } v;
  v.f = f;
  unsigned r = v.u + 0x7fffu + ((v.u >> 16) & 1u);
  return (unsigned short)(r >> 16);
}
__device__ __forceinline__ float bf2f(unsigned h) {
  union { unsigned u; float f; } v;
  v.u = h << 16;
  return v.f;
}
// unpack packed bf16 pair (lo,hi) of one uint into f32x2
__device__ __forceinline__ f32x2 unpk(uint u) {
  union { uint u; float f; } lo, hi;
  lo.u = u << 16;
  hi.u = u & 0xffff0000u;
  f32x2 r;
  r.x = lo.f;
  r.y = hi.f;
  return r;
}
__device__ __forceinline__ uint pk2(f32x2 v) { return (uint)f2bf(v.x) | ((uint)f2bf(v.y) << 16); }
__device__ __forceinline__ f32x2 red2_1632(f32x2 v) {
  v.x += __shfl_xor(v.x, 16, 64);
  v.y += __shfl_xor(v.y, 16, 64);
  v.x += __shfl_xor(v.x, 32, 64);
  v.y += __shfl_xor(v.y, 32, 64);
  return v;
}

// ==== CSR build, hierarchical, no global atomics, saturated grids ====
__global__ __launch_bounds__(1024) void hist_part(const int* __restrict__ ei, int* __restrict__ part) {
  __shared__ int cnt[VV];
  const int t = blockIdx.x / PP, p = blockIdx.x % PP;
  const int tid = threadIdx.x;
  for (int i = tid; i < VV; i += 1024) cnt[i] = 0;
  __syncthreads();
  const int* dstp = ei + (long)(t * 2 + 1) * EE + p * CHUNK;
  for (int e = tid; e < CHUNK; e += 1024) atomicAdd(&cnt[dstp[e]], 1);
  __syncthreads();
  int* op = part + (long)blockIdx.x * VV;
  for (int i = tid; i < VV; i += 1024) op[i] = cnt[i];
}

__global__ __launch_bounds__(256) void part_prefix(int* __restrict__ part, int* __restrict__ cnt) {
  int idx = blockIdx.x * 256 + threadIdx.x;  // t*VV + v
  if (idx >= RR) return;
  int t = idx / VV, v = idx - t * VV;
  long base = ((long)t * PP) * VV + v;
  int x[PP];
#pragma unroll
  for (int p = 0; p < PP; p++) x[p] = part[base + (long)p * VV];
  int s = 0;
#pragma unroll
  for (int p = 0; p < PP; p++) {
    int xx = x[p];
    part[base + (long)p * VV] = s;
    s += xx;
  }
  cnt[idx] = s;
}

__global__ __launch_bounds__(256) void scan_block(const int* __restrict__ cnt, int* __restrict__ off,
                                                  int* __restrict__ bsum) {
  __shared__ int sm[256];
  int i = blockIdx.x * 256 + threadIdx.x;
  int v = (i < RR) ? cnt[i] : 0;
  sm[threadIdx.x] = v;
  __syncthreads();
  for (int d = 1; d < 256; d <<= 1) {
    int t = (threadIdx.x >= d) ? sm[threadIdx.x - d] : 0;
    __syncthreads();
    sm[threadIdx.x] += t;
    __syncthreads();
  }
  if (i < RR) off[i] = sm[threadIdx.x] - v;
  if (threadIdx.x == 255) bsum[blockIdx.x] = sm[255];
}

__global__ __launch_bounds__(512) void scan_tops(int* __restrict__ bsum, int nb) {
  __shared__ int sm[512];
  int v = (threadIdx.x < nb) ? bsum[threadIdx.x] : 0;
  sm[threadIdx.x] = v;
  __syncthreads();
  for (int d = 1; d < 512; d <<= 1) {
    int t = (threadIdx.x >= d) ? sm[threadIdx.x - d] : 0;
    __syncthreads();
    sm[threadIdx.x] += t;
    __syncthreads();
  }
  if (threadIdx.x < nb) bsum[threadIdx.x] = sm[threadIdx.x] - v;
}

__global__ __launch_bounds__(256) void scan_add(int* __restrict__ off, const int* __restrict__ bsum) {
  int i = blockIdx.x * 256 + threadIdx.x;
  if (i < RR) off[i] += bsum[blockIdx.x];
  if (i == 0) off[RR] = TT * EE;
}

__global__ __launch_bounds__(1024) void scatter_part(const int* __restrict__ ei, const int* __restrict__ off,
                                                     const int* __restrict__ part, int* __restrict__ csr) {
  __shared__ int base_s[VV];
  __shared__ int cnt[VV];
  const int t = blockIdx.x / PP, p = blockIdx.x % PP;
  const int tid = threadIdx.x;
  const int* pp = part + (long)blockIdx.x * VV;
  const int* offt = off + t * VV;
  for (int i = tid; i < VV; i += 1024) {
    base_s[i] = offt[i] + pp[i];
    cnt[i] = 0;
  }
  __syncthreads();
  const int* srcp = ei + (long)(t * 2) * EE + p * CHUNK;
  const int* dstp = ei + (long)(t * 2 + 1) * EE + p * CHUNK;
  for (int e = tid; e < CHUNK; e += 1024) {
    int d = dstp[e];
    int r = atomicAdd(&cnt[d], 1);
    csr[base_s[d] + r] = t * VV + srcp[e];
  }
}

// ---- cast xs -> A_hi[:,0:128] (bf16 hi), A_lo[:,0:128] (bf16 lo) ----
__global__ __launch_bounds__(256) void cast_x0(const float* __restrict__ xs, unsigned short* __restrict__ Ahi,
                                               unsigned short* __restrict__ Alo) {
  int idx = blockIdx.x * 256 + threadIdx.x;  // one per float4, RR*32 total
  int row = idx >> 5, c4 = (idx & 31) * 4;
  float4 v = *reinterpret_cast<const float4*>(&xs[(long)row * 128 + c4]);
  ushort4 hs, ls;
  hs.x = f2bf(v.x); hs.y = f2bf(v.y); hs.z = f2bf(v.z); hs.w = f2bf(v.w);
  ls.x = f2bf(v.x - bf2f(hs.x)); ls.y = f2bf(v.y - bf2f(hs.y));
  ls.z = f2bf(v.z - bf2f(hs.z)); ls.w = f2bf(v.w - bf2f(hs.w));
  *reinterpret_cast<ushort4*>(&Ahi[(long)row * 256 + c4]) = hs;
  *reinterpret_cast<ushort4*>(&Alo[(long)row * 128 + c4]) = ls;
}

// ---- build stacked bf16 weight matrix Bp[n][k] (transposed, row stride Ktot) + bias ----
__global__ __launch_bounds__(256) void prep_b(const float* __restrict__ Wl, const float* __restrict__ Wr,
                                              const float* __restrict__ Wres, const float* __restrict__ bc,
                                              const float* __restrict__ bres, int Cin, int Ktot,
                                              unsigned short* __restrict__ Bp, float* __restrict__ bias) {
  int idx = blockIdx.x * 256 + threadIdx.x;
  if (idx >= NOUT * Ktot) return;
  int n = idx / Ktot, k = idx - n * Ktot;
  int reg = k / Cin, kk = k - reg * Cin;
  float w;
  if (reg == 1)
    w = (n < 160) ? Wr[kk * 160 + n] : 0.f;
  else
    w = (n < 160) ? Wl[kk * 160 + n] : Wres[kk * 64 + (n - 160)];
  Bp[idx] = f2bf(w);
  if (k == 0) bias[n] = (n < 160) ? bc[n] : bres[n - 160];
}

// ---- gather layer 0: 16-lane edge-groups, 8 edges in flight, XCD-swizzled ----
__global__ __launch_bounds__(256) void gather0(const int* __restrict__ off, const int* __restrict__ csr,
                                               const uint4* __restrict__ X4, uint4* __restrict__ M4) {
  int sb = (blockIdx.x & 7) * 2500 + (blockIdx.x >> 3);  // bijective: 20000 = 8*2500
  int wv = __builtin_amdgcn_readfirstlane(threadIdx.x) >> 6;
  int lane = threadIdx.x & 63;
  int row = sb * 4 + wv;
  int s = off[row], e = off[row + 1];
  int sub = lane >> 4, c = lane & 15;
  f32x2 a0 = {0.f, 0.f}, a1 = a0, a2 = a0, a3 = a0;
  int i = s;
  for (; i + 8 <= e; i += 8) {
    int g0 = csr[i + sub];
    int g1 = csr[i + 4 + sub];
    uint4 w0 = X4[(long)g0 * 32 + c];
    uint4 w1 = X4[(long)g1 * 32 + c];
    a0 += unpk(w0.x) + unpk(w1.x);
    a1 += unpk(w0.y) + unpk(w1.y);
    a2 += unpk(w0.z) + unpk(w1.z);
    a3 += unpk(w0.w) + unpk(w1.w);
  }
  for (; i + 4 <= e; i += 4) {
    int g = csr[i + sub];
    uint4 w = X4[(long)g * 32 + c];
    a0 += unpk(w.x);
    a1 += unpk(w.y);
    a2 += unpk(w.z);
    a3 += unpk(w.w);
  }
  if (i + sub < e) {
    int g = csr[i + sub];
    uint4 w = X4[(long)g * 32 + c];
    a0 += unpk(w.x);
    a1 += unpk(w.y);
    a2 += unpk(w.z);
    a3 += unpk(w.w);
  }
  a0 = red2_1632(a0);
  a1 = red2_1632(a1);
  a2 = red2_1632(a2);
  a3 = red2_1632(a3);
  if (sub == 0) {
    float inv = 1.f / (float)max(e - s, 1);
    uint4 o;
    o.x = pk2(a0 * inv);
    o.y = pk2(a1 * inv);
    o.z = pk2(a2 * inv);
    o.w = pk2(a3 * inv);
    M4[(long)row * 32 + 16 + c] = o;
  }
}

// ---- gather layer 1: 16-lane edge-groups, 8 edges in flight, XCD-swizzled ----
__global__ __launch_bounds__(256) void gather1(const int* __restrict__ off, const int* __restrict__ csr,
                                               const uint2* __restrict__ X2, uint2* __restrict__ M2) {
  int sb = (blockIdx.x & 7) * 2500 + (blockIdx.x >> 3);
  int wv = __builtin_amdgcn_readfirstlane(threadIdx.x) >> 6;
  int lane = threadIdx.x & 63;
  int row = sb * 4 + wv;
  int s = off[row], e = off[row + 1];
  int sub = lane >> 4, c = lane & 15;
  f32x2 a0 = {0.f, 0.f}, a1 = a0;
  int i = s;
  for (; i + 8 <= e; i += 8) {
    int g0 = csr[i + sub];
    int g1 = csr[i + 4 + sub];
    uint2 w0 = X2[(long)g0 * 64 + c];
    uint2 w1 = X2[(long)g1 * 64 + c];
    a0 += unpk(w0.x) + unpk(w1.x);
    a1 += unpk(w0.y) + unpk(w1.y);
  }
  for (; i + 4 <= e; i += 4) {
    int g = csr[i + sub];
    uint2 w = X2[(long)g * 64 + c];
    a0 += unpk(w.x);
    a1 += unpk(w.y);
  }
  if (i + sub < e) {
    int g = csr[i + sub];
    uint2 w = X2[(long)g * 64 + c];
    a0 += unpk(w.x);
    a1 += unpk(w.y);
  }
  a0 = red2_1632(a0);
  a1 = red2_1632(a1);
  if (sub == 0) {
    float inv = 1.f / (float)max(e - s, 1);
    uint2 o;
    o.x = pk2(a0 * inv);
    o.y = pk2(a1 * inv);
    M2[(long)row * 64 + 16 + c] = o;
  }
}

// ==== bf16x2 MFMA GEMM: 64x224 tile, 2x36KB LDS -> 2 blocks/CU ====
// Halved tile vs R11 config: same BK=64, same row&7 swizzle on 128B rows, acc 28 VGPR.
// 2 co-resident blocks/CU hide each other's vmcnt/barrier stalls.
// Staging: 36 chunks of 1024B (A:0-7, B:8-35); 5 loads/wave with chunk-35
// duplicated for waves 4-7 (same src->same dest, benign) so vmcnt(5) is uniform.
__device__ __forceinline__ void stage_tile(char* sb, const unsigned short* aptr, long astr,
                                           const unsigned short* Bp, int Ktot, int k0, long row0,
                                           int wid, int lane) {
#pragma unroll
  for (int r = 0; r < 5; ++r) {
    int c = wid + r * 8;  // 0..39, wave-uniform
    if (c > 35) c = 35;   // benign duplicate load of last chunk
    const char* gp;
    if (c < 8) {
      int o = c * 1024 + lane * 16;
      int arow = o >> 7;   // 0..63
      int ac16 = (o >> 4) & 7;
      gp = (const char*)aptr + ((row0 + arow) * astr) * 2 + ((ac16 ^ (arow & 7)) << 4);
    } else {
      int o = (c - 8) * 1024 + lane * 16;
      int brow = o >> 7;   // 0..223, no clamp needed
      int bc16 = (o >> 4) & 7;
      gp = (const char*)Bp + ((long)brow * Ktot + k0) * 2 + ((bc16 ^ (brow & 7)) << 4);
    }
    __builtin_amdgcn_global_load_lds((const GLOBAL_AS uint*)gp, (LDS_AS uint*)(sb + c * 1024), 16, 0, 0);
  }
}

__global__ __launch_bounds__(512) void gemm_kernel(const unsigned short* __restrict__ Ahi,
                                                   const unsigned short* __restrict__ Alo,
                                                   const unsigned short* __restrict__ Bp,
                                                   const float* __restrict__ bias, float* __restrict__ outs,
                                                   int Ktot, int sw1, int lda, int ldalo) {
  __shared__ char sbuf[2][36864];
  const int tid = threadIdx.x;
  const long row0 = (long)blockIdx.x * 64;
  const int wid = tid >> 6, lane = tid & 63;
  const int wr = wid >> 1, wc = wid & 1;  // wave = 16 rows x 112 cols
  const int l15 = lane & 15, lg = lane >> 4;
  f32x4 acc[7];
#pragma unroll
  for (int n = 0; n < 7; n++) acc[n] = (f32x4)(0.f);

  const int nt = Ktot / 64;
  auto asel = [&](int k0, const unsigned short*& aptr, long& astr) {
    if (k0 < sw1) { aptr = Ahi + k0; astr = lda; }
    else { aptr = Alo + (k0 - sw1); astr = ldalo; }
  };
  {
    const unsigned short* aptr; long astr;
    asel(0, aptr, astr);
    stage_tile(sbuf[0], aptr, astr, Bp, Ktot, 0, row0, wid, lane);
  }
  for (int kt = 0; kt < nt; ++kt) {
    const int b = kt & 1;
    if (kt + 1 < nt) {
      const unsigned short* aptr; long astr;
      asel((kt + 1) * 64, aptr, astr);
      stage_tile(sbuf[b ^ 1], aptr, astr, Bp, Ktot, (kt + 1) * 64, row0, wid, lane);
      asm volatile("s_waitcnt vmcnt(5)" ::: "memory");  // current buf's 5 loads landed
    } else {
      asm volatile("s_waitcnt vmcnt(0)" ::: "memory");
    }
    __builtin_amdgcn_s_barrier();
    __builtin_amdgcn_sched_barrier(0);
    const char* sb = sbuf[b];
#pragma unroll
    for (int kk = 0; kk < 2; ++kk) {
      const int cswz = (((kk << 2) | lg) ^ (l15 & 7)) << 4;
      bf16x8 af = *reinterpret_cast<const bf16x8*>(sb + (wr * 16 + l15) * 128 + cswz);
#pragma unroll
      for (int n = 0; n < 7; ++n) {
        bf16x8 bfr = *reinterpret_cast<const bf16x8*>(sb + 8192 + (wc * 112 + n * 16 + l15) * 128 + cswz);
        acc[n] = __builtin_amdgcn_mfma_f32_16x16x32_bf16(af, bfr, acc[n], 0, 0, 0);
      }
    }
    __builtin_amdgcn_sched_barrier(0);
    __builtin_amdgcn_s_barrier();  // all waves done reading buf b (next iter overwrites it)
  }
  long grow = row0 + wr * 16 + lg * 4;
#pragma unroll
  for (int n = 0; n < 7; n++) {
    int gcol = wc * 112 + n * 16 + l15;
    float bv = bias[gcol];
#pragma unroll
    for (int r = 0; r < 4; r++) outs[(grow + r) * NOUT + gcol] = acc[n][r] + bv;
  }
}

// ---- diagonal SSM scan over T, f32x2 packed math ----
// MODE 0: tkmix + write bf16 hi/lo all T. MODE 1: last-T only + fused final matmul.
template <int MODE>
__global__ __launch_bounds__(256, 4) void ssm_kernel(const float* __restrict__ outs, const float* __restrict__ logA,
                                                     const float* __restrict__ dlt, const float* __restrict__ tkw,
                                                     const float* __restrict__ tkb, unsigned short* __restrict__ xhi,
                                                     unsigned short* __restrict__ xlo, const float* __restrict__ Wmlp,
                                                     const float* __restrict__ bmlp, float* __restrict__ out) {
  __shared__ float ylds[4][64];  // MODE 1 only
  int wv = __builtin_amdgcn_readfirstlane(threadIdx.x) >> 6;  // wave-uniform wave id
  int v = blockIdx.x * 4 + wv;
  int h = threadIdx.x & 63;
  f32x2 a2v[8], sv[8];
#pragma unroll
  for (int p = 0; p < 8; p++) {
    a2v[p].x = -__expf(logA[h * NN + 2 * p]) * 1.44269504f;
    a2v[p].y = -__expf(logA[h * NN + 2 * p + 1]) * 1.44269504f;
    sv[p] = (f32x2){0.f, 0.f};
  }
  float dh = dlt[h];
  float w0 = 0.f, w1 = 0.f, w2 = 0.f, tb = 0.f;
  float xhm = 0.f, xh0 = 0.f;
  if (MODE == 0) {
    w0 = tkw[h * 3 + 0];
    w1 = tkw[h * 3 + 1];
    w2 = tkw[h * 3 + 2];
    tb = tkb[h];
  }
  const float* rp = outs + (long)v * NOUT;
  float dtr_c = rp[HH + h] + dh;
  float xvh_c = rp[h];
  float rres_c = rp[160 + h];
  float4 qb_c[4], qc_c[4];
  {
    const float4* bc4 = reinterpret_cast<const float4*>(rp + 2 * HH);
    qb_c[0] = bc4[0]; qb_c[1] = bc4[1]; qb_c[2] = bc4[2]; qb_c[3] = bc4[3];
    if (MODE == 0) { qc_c[0] = bc4[4]; qc_c[1] = bc4[5]; qc_c[2] = bc4[6]; qc_c[3] = bc4[7]; }
  }
  if (MODE == 0) xh0 = xvh_c;
#pragma unroll
  for (int t = 0; t < TT; t++) {
    const float* rpn = rp + (long)VV * NOUT;
    float dtr_n = 0.f, xvh_n = 0.f, rres_n = 0.f;
    float4 qb_n[4], qc_n[4];
    if (t + 1 < TT) {
      dtr_n = rpn[HH + h] + dh;
      xvh_n = rpn[h];
      rres_n = rpn[160 + h];
      const float4* bc4n = reinterpret_cast<const float4*>(rpn + 2 * HH);
      qb_n[0] = bc4n[0]; qb_n[1] = bc4n[1]; qb_n[2] = bc4n[2]; qb_n[3] = bc4n[3];
      if (MODE == 0) { qc_n[0] = bc4n[4]; qc_n[1] = bc4n[5]; qc_n[2] = bc4n[6]; qc_n[3] = bc4n[7]; }
    }
    float dtr = dtr_c;
    float dt = dtr > 20.f ? dtr : __logf(1.f + __expf(dtr));
    float xv;
    if (MODE == 0) {
      float xh1 = (t + 1 < TT) ? xvh_n : 0.f;
      xv = fmaf(xhm, w0, fmaf(xh0, w1, fmaf(xh1, w2, tb)));
      xhm = xh0;
      xh0 = xh1;
    } else {
      xv = xvh_c;
    }
    f32x2 bbv[8] = {{qb_c[0].x, qb_c[0].y}, {qb_c[0].z, qb_c[0].w}, {qb_c[1].x, qb_c[1].y}, {qb_c[1].z, qb_c[1].w},
                    {qb_c[2].x, qb_c[2].y}, {qb_c[2].z, qb_c[2].w}, {qb_c[3].x, qb_c[3].y}, {qb_c[3].z, qb_c[3].w}};
    float dtxv = dt * xv;
#pragma unroll
    for (int p = 0; p < 8; p++) {
      f32x2 arg = a2v[p] * dt;
      f32x2 e = {exp2f(arg.x), exp2f(arg.y)};
      sv[p] = e * sv[p] + bbv[p] * dtxv;
    }
    const bool needY = (MODE == 0) || (t == TT - 1);
    if (needY) {
      float4 c0, c1, c2, c3;
      if (MODE == 0) {
        c0 = qc_c[0]; c1 = qc_c[1]; c2 = qc_c[2]; c3 = qc_c[3];
      } else {
        const float4* bc4 = reinterpret_cast<const float4*>(rp + 2 * HH);
        c0 = bc4[4]; c1 = bc4[5]; c2 = bc4[6]; c3 = bc4[7];
      }
      f32x2 ccv[8] = {{c0.x, c0.y}, {c0.z, c0.w}, {c1.x, c1.y}, {c1.z, c1.w},
                      {c2.x, c2.y}, {c2.z, c2.w}, {c3.x, c3.y}, {c3.z, c3.w}};
      f32x2 yv = {0.f, 0.f};
#pragma unroll
      for (int p = 0; p < 8; p++) yv += sv[p] * ccv[p];
      float y = fmaxf(yv.x + yv.y, 0.f);
      float z = y + rres_c;
      float s1 = z, s2 = z * z;
#pragma unroll
      for (int m = 32; m > 0; m >>= 1) {
        s1 += __shfl_xor(s1, m, 64);
        s2 += __shfl_xor(s2, m, 64);
      }
      float mu = s1 * (1.f / 64.f);
      float var = fmaf(s2, 1.f / 64.f, -mu * mu);
      float o = (z - mu) * rsqrtf(var + 1e-5f);
      if (MODE == 0) {
        long row = (long)t * VV + v;
        unsigned short hi = f2bf(o);
        xhi[row * 256 + h] = hi;
        xlo[row * 128 + h] = f2bf(o - bf2f(hi));
      } else {
        ylds[wv][h] = o;
      }
    }
    dtr_c = dtr_n;
    xvh_c = xvh_n;
    rres_c = rres_n;
    qb_c[0] = qb_n[0]; qb_c[1] = qb_n[1]; qb_c[2] = qb_n[2]; qb_c[3] = qb_n[3];
    if (MODE == 0) { qc_c[0] = qc_n[0]; qc_c[1] = qc_n[1]; qc_c[2] = qc_n[2]; qc_c[3] = qc_n[3]; }
    rp = rpn;
  }
  if (MODE == 1) {
    __syncthreads();
    float acc = bmlp[h];
#pragma unroll 8
    for (int h2 = 0; h2 < 64; h2++) acc = fmaf(ylds[wv][h2], Wmlp[h2 * CO + h], acc);
    out[(long)v * CO + h] = acc;
  }
}

extern "C" void kernel_launch(void* const* d_in, const int* in_sizes, int n_in, void* d_out, int out_size,
                              void* d_ws, size_t ws_size, hipStream_t stream) {
  const float* xs = (const float*)d_in[0];
  const int* ei = (const int*)d_in[1];
  const float* Wl0 = (const float*)d_in[2];
  const float* Wr0 = (const float*)d_in[3];
  const float* bc0 = (const float*)d_in[4];
  const float* Wl1 = (const float*)d_in[5];
  const float* Wr1 = (const float*)d_in[6];
  const float* bc1 = (const float*)d_in[7];
  const float* Wres0 = (const float*)d_in[8];
  const float* bres0 = (const float*)d_in[9];
  const float* Wres1 = (const float*)d_in[10];
  const float* bres1 = (const float*)d_in[11];
  const float* tkw = (const float*)d_in[12];
  const float* tkb = (const float*)d_in[13];
  const float* logA = (const float*)d_in[14];
  const float* dlt = (const float*)d_in[15];
  const float* Wmlp = (const float*)d_in[16];
  const float* bmlp = (const float*)d_in[17];
  float* out = (float*)d_out;

  float* outs = (float*)d_ws;                          // RR*224 f32
  unsigned short* Ahi = (unsigned short*)(outs + (long)RR * NOUT);  // RR*256 bf16
  unsigned short* Alo = Ahi + (long)RR * 256;          // RR*128 bf16
  unsigned short* Bp0 = Alo + (long)RR * 128;          // 224*384
  unsigned short* Bp1 = Bp0 + 224 * 384;               // 224*192
  float* bias0 = (float*)(Bp1 + 224 * 192);            // 224
  float* bias1 = bias0 + 224;                          // 224
  int* off = (int*)(bias1 + 224);                      // RR+1
  int* csr = off + RR + 1;                             // TT*EE
  int* cnt = csr + TT * EE;                            // RR
  int* bsum = cnt + RR;                                // 512
  // part[256][VV] aliases outs: dead before the first gemm writes outs.
  int* part = (int*)outs;

  const int NB = (RR + 255) / 256;  // 313

  // ---- CSR build: 6 kernels, LDS histograms, no global atomics, saturated ----
  hist_part<<<TT * PP, 1024, 0, stream>>>(ei, part);
  part_prefix<<<NB, 256, 0, stream>>>(part, cnt);
  scan_block<<<NB, 256, 0, stream>>>(cnt, off, bsum);
  scan_tops<<<1, 512, 0, stream>>>(bsum, NB);
  scan_add<<<NB, 256, 0, stream>>>(off, bsum);
  scatter_part<<<TT * PP, 1024, 0, stream>>>(ei, off, part, csr);

  // ---- weight prep (hi-only, bf16x2) ----
  prep_b<<<(NOUT * 384 + 255) / 256, 256, 0, stream>>>(Wl0, Wr0, Wres0, bc0, bres0, 128, 384, Bp0, bias0);
  prep_b<<<(NOUT * 192 + 255) / 256, 256, 0, stream>>>(Wl1, Wr1, Wres1, bc1, bres1, 64, 192, Bp1, bias1);

  // ---- layer 0: K = 256 (x_hi|mean) + 128 (x_lo) ----
  cast_x0<<<RR * 32 / 256, 256, 0, stream>>>(xs, Ahi, Alo);
  gather0<<<RR / 4, 256, 0, stream>>>(off, csr, (const uint4*)Ahi, (uint4*)Ahi);
  gemm_kernel<<<RR / 64, 512, 0, stream>>>(Ahi, Alo, Bp0, bias0, outs, 384, 256, 256, 128);
  ssm_kernel<0><<<VV / 4, 256, 0, stream>>>(outs, logA, dlt, tkw, tkb, Ahi, Alo, nullptr, nullptr, nullptr);

  // ---- layer 1: K = 128 (x_hi|mean) + 64 (x_lo); ssm fuses final matmul ----
  gather1<<<RR / 4, 256, 0, stream>>>(off, csr, (const uint2*)Ahi, (uint2*)Ahi);
  gemm_kernel<<<RR / 64, 512, 0, stream>>>(Ahi, Alo, Bp1, bias1, outs, 192, 128, 256, 128);
  ssm_kernel<1><<<VV / 4, 256, 0, stream>>>(outs, logA + HH * NN, dlt + HH, nullptr, nullptr, nullptr, nullptr,
                                            Wmlp, bmlp, out);
}